// Round 17
// baseline (116.188 us; speedup 1.0000x reference)
//
#include <hip/hip_runtime.h>
#include <stdint.h>

typedef unsigned short u16;
typedef __attribute__((ext_vector_type(8))) short short8;
typedef __attribute__((ext_vector_type(4))) float f32x4;
typedef __attribute__((ext_vector_type(4))) unsigned short ushort4v;
typedef __attribute__((ext_vector_type(2))) unsigned int uint2v;

#define NB 2
#define NS 2048
#define ND 1024
#define NH 16
#define HDIM 64
#define NHALF 32
#define QSCALE 0.18033688f   /* 0.125 * log2(e) : folds 1/sqrt(64) and exp->exp2 */
#define NEGBIG -3.0e38f      /* finite "-inf": exp2 -> 0, no NaN from arithmetic */

__device__ __forceinline__ float bf2f(u16 u) {
  union { unsigned u; float f; } v; v.u = ((unsigned)u) << 16; return v.f;
}
__device__ __forceinline__ u16 f2bf(float f) {
  union { float f; unsigned u; } v; v.f = f;
  unsigned r = v.u + 0x7fffu + ((v.u >> 16) & 1u);
  return (u16)(r >> 16);
}

// packs lo->bits[15:0], hi->bits[31:16], RNE — same rounding as f2bf
__device__ __forceinline__ unsigned cvt_pk_bf16(float lo, float hi) {
  unsigned r;
  asm("v_cvt_pk_bf16_f32 %0, %1, %2" : "=v"(r) : "v"(lo), "v"(hi));
  return r;
}

__device__ __forceinline__ void gld_lds16(const u16* g, u16* l) {
  void* gv = (void*)g;
  __builtin_amdgcn_global_load_lds((__attribute__((address_space(1))) void*)gv,
                                   (__attribute__((address_space(3))) void*)l, 16, 0, 0);
}

// ---------------- prep: transpose + convert the 4 weights (4096 blocks) ----------------
__global__ void prep_w(const float* __restrict__ W0, const float* __restrict__ W1,
                       const float* __restrict__ W2, const float* __restrict__ W3,
                       u16* __restrict__ dqkv, u16* __restrict__ dout) {
  __shared__ float tile[32][33];
  int idx = blockIdx.x;
  const int z = idx >> 10;
  idx &= 1023;
  const int bx = idx & 31, by = idx >> 5;
  const float* W = (z == 0) ? W0 : (z == 1) ? W1 : (z == 2) ? W2 : W3;
  u16* dst = (z < 3) ? (dqkv + (size_t)z * ND * ND) : dout;
  const int n0 = bx * 32, k0 = by * 32;
  const int tx = threadIdx.x & 31, ty = threadIdx.x >> 5;   // 32x8
#pragma unroll
  for (int i = 0; i < 4; ++i)
    tile[ty + i * 8][tx] = W[(size_t)(k0 + ty + i * 8) * ND + n0 + tx];
  __syncthreads();
#pragma unroll
  for (int i = 0; i < 4; ++i)
    dst[(size_t)(n0 + ty + i * 8) * ND + k0 + tx] = f2bf(tile[tx][ty + i * 8]);
}

// ---------------- shared GEMM body, BK=64, XOR-swizzled + double-buffered LDS ----------------
// MODE 0 (QK): A read DIRECTLY from fp32 x (T14 async reg-staging: loads early,
//   cvt_pk + swizzled ds_write late). Operand-SWAPPED MFMA -> RoPE fused, 8B stores.
// MODE 1 (V):  fp32-A path too; normal orientation, direct VT [b][h][d][s] stores.
// MODE 2 (out): bf16 A via global_load_lds (proven path); fp32 row output.
template<int MI, int MODE>
__device__ __forceinline__ void gemm_body(
    u16* smem0, int bx, int by,
    const float* __restrict__ Xf, const u16* __restrict__ A,
    const u16* __restrict__ BT,
    u16* __restrict__ qo, u16* __restrict__ ko, u16* __restrict__ vo,
    float* __restrict__ fo,
    const float* __restrict__ cosT, const float* __restrict__ sinT) {
  constexpr int BUFSZ = MI * 2048 + 8192;
  constexpr int LA = MI * 2;                 // float4 chunks per thread per A-stage
  const int tid = threadIdx.x;
  const int w = tid >> 6, lane = tid & 63;
  const int lr = lane & 15, lg = lane >> 4;
  const int bm = by * (MI * 32), bn = bx << 7;
  const int wr = (w >> 1) * (MI * 16), wc = (w & 1) << 6;
  f32x4 acc[MI][4] = {};

  // B staging source (bf16, inverse-swizzled global col)
  const int arow = tid >> 3;
  const int aslot = (tid & 7) ^ (arow & 7);
  const u16* bgs = BT + (size_t)(bn + arow) * ND + (aslot << 3);
  // bf16 A staging source (MODE 2 only)
  const u16* ags = (MODE == 2) ? (A + (size_t)(bm + arow) * ND + (aslot << 3)) : nullptr;
  // fp32 A staging source (MODE 0/1): thread covers rows i*16+(tid>>4), cols 4*(tid&15)..+3
  const float* axs = (MODE != 2)
      ? (Xf + (size_t)(bm + (tid >> 4)) * ND + ((tid & 15) << 2)) : nullptr;

  int af_off[MI][2], bf_off[4][2];
#pragma unroll
  for (int mi = 0; mi < MI; ++mi)
#pragma unroll
    for (int kk = 0; kk < 2; ++kk)
      af_off[mi][kk] = (wr + mi * 16 + lr) * 64 + ((((kk << 2) + lg) ^ (lr & 7)) << 3);
#pragma unroll
  for (int ni = 0; ni < 4; ++ni)
#pragma unroll
    for (int kk = 0; kk < 2; ++kk)
      bf_off[ni][kk] = (wc + ni * 16 + lr) * 64 + ((((kk << 2) + lg) ^ (lr & 7)) << 3);

  float4 areg[LA];
  auto loadA = [&](int kt) {                 // issue early: latency hides under MFMA
#pragma unroll
    for (int i = 0; i < LA; ++i)
      areg[i] = *(const float4*)(axs + (size_t)i * 16 * ND + kt);
  };
  auto writeA = [&](int buf) {               // cvt + swizzled LDS write (after compute)
    u16* dst = smem0 + buf * BUFSZ;
    const int g = tid & 15;                  // 8B-granule col index
    const int slotbase = g >> 1;
    const int hoff = (g & 1) * 4;            // u16 offset within 16B slot
#pragma unroll
    for (int i = 0; i < LA; ++i) {
      const int row = i * 16 + (tid >> 4);
      const int slot = slotbase ^ (row & 7);
      uint2v pk;
      pk.x = cvt_pk_bf16(areg[i].x, areg[i].y);
      pk.y = cvt_pk_bf16(areg[i].z, areg[i].w);
      *(uint2v*)(dst + row * 64 + slot * 8 + hoff) = pk;
    }
  };
  auto stageB = [&](int buf, int kt) {
    u16* dst = smem0 + buf * BUFSZ + MI * 2048;
#pragma unroll
    for (int it = 0; it < 4; ++it)
      gld_lds16(bgs + it * (32 * ND) + kt, dst + it * 2048 + w * 512);
  };
  auto stageA16 = [&](int buf, int kt) {     // MODE 2: bf16 A via global_load_lds
    u16* dst = smem0 + buf * BUFSZ;
#pragma unroll
    for (int it = 0; it < MI; ++it)
      gld_lds16(ags + it * (32 * ND) + kt, dst + it * 2048 + w * 512);
  };

  // prologue
  if constexpr (MODE != 2) loadA(0);
  stageB(0, 0);
  if constexpr (MODE == 2) stageA16(0, 0);
  if constexpr (MODE != 2) writeA(0);
  __syncthreads();

  int cur = 0;
  for (int kt = 0; kt < ND; kt += 64) {
    const bool more = kt + 64 < ND;
    if (more) {
      if constexpr (MODE != 2) loadA(kt + 64);
      stageB(cur ^ 1, kt + 64);
      if constexpr (MODE == 2) stageA16(cur ^ 1, kt + 64);
    }
    const u16* As = smem0 + cur * BUFSZ;
    const u16* Bs = As + MI * 2048;
#pragma unroll
    for (int kk = 0; kk < 2; ++kk) {
      short8 af[MI], bfr[4];
#pragma unroll
      for (int mi = 0; mi < MI; ++mi)
        af[mi] = *(const short8*)(As + af_off[mi][kk]);
#pragma unroll
      for (int ni = 0; ni < 4; ++ni)
        bfr[ni] = *(const short8*)(Bs + bf_off[ni][kk]);
#pragma unroll
      for (int mi = 0; mi < MI; ++mi)
#pragma unroll
        for (int ni = 0; ni < 4; ++ni) {
          if (MODE == 0)   // swapped operands: acc = (x@W)^T fragment
            acc[mi][ni] = __builtin_amdgcn_mfma_f32_16x16x32_bf16(bfr[ni], af[mi], acc[mi][ni], 0, 0, 0);
          else
            acc[mi][ni] = __builtin_amdgcn_mfma_f32_16x16x32_bf16(af[mi], bfr[ni], acc[mi][ni], 0, 0, 0);
        }
    }
    if (more) { if constexpr (MODE != 2) writeA(cur ^ 1); }
    __syncthreads();
    cur ^= 1;
  }

  if (MODE == 0) {
    // acc[mi][ni][j]: row = n (d-dim), col = s = bm+wr+mi*16+lr
#pragma unroll
    for (int mi = 0; mi < MI; ++mi) {
      const int m = bm + wr + mi * 16 + lr;
      const int b = m >> 11, s = m & 2047;
      const float* cbase = cosT + s * NHALF;
      const float* sbase = sinT + s * NHALF;
#pragma unroll
      for (int ni = 0; ni < 4; ++ni) {
        const int n = bn + wc + ni * 16 + (lg << 2);
        const int which = n >> 10, hh = (n >> 6) & 15, d0 = n & 63;
        u16* dst = which == 0 ? qo : ko;
        const float sc = which == 0 ? QSCALE : 1.0f;
        const float2 cp = *(const float2*)(cbase + (d0 >> 1));
        const float2 sp = *(const float2*)(sbase + (d0 >> 1));
        const float v0 = acc[mi][ni][0], v1 = acc[mi][ni][1];
        const float v2 = acc[mi][ni][2], v3 = acc[mi][ni][3];
        uint2v pk;
        pk.x = cvt_pk_bf16((v0 * cp.x - v1 * sp.x) * sc, (v0 * sp.x + v1 * cp.x) * sc);
        pk.y = cvt_pk_bf16((v2 * cp.y - v3 * sp.y) * sc, (v2 * sp.y + v3 * cp.y) * sc);
        *(uint2v*)(dst + (((size_t)(b * NH + hh) * NS + s) << 6) + d0) = pk;
      }
    }
  } else if (MODE == 1) {
#pragma unroll
    for (int mi = 0; mi < MI; ++mi) {
#pragma unroll
      for (int ni = 0; ni < 4; ++ni) {
        const int n = bn + wc + ni * 16 + lr;
        const int hh = n >> 6, d = n & 63;
        const int m0 = bm + wr + mi * 16 + (lg << 2);
        const int b = m0 >> 11, s0 = m0 & 2047;
        uint2v pk;
        pk.x = cvt_pk_bf16(acc[mi][ni][0], acc[mi][ni][1]);
        pk.y = cvt_pk_bf16(acc[mi][ni][2], acc[mi][ni][3]);
        *(uint2v*)(vo + ((size_t)(b * NH + hh) * HDIM + d) * NS + s0) = pk;
      }
    }
  } else {
#pragma unroll
    for (int mi = 0; mi < MI; ++mi)
#pragma unroll
      for (int ni = 0; ni < 4; ++ni)
#pragma unroll
        for (int j = 0; j < 4; ++j) {
          const int m = bm + wr + mi * 16 + (lg << 2) + j;
          const int n = bn + wc + ni * 16 + lr;
          fo[(size_t)m * ND + n] = acc[mi][ni][j];
        }
  }
}

// Merged QKV projection with XCD-aware bijective swizzle:
// QK (bids 0..511): n-tile = (bid&7)*2 + bit3 -> each XCD owns 2 B-panels;
//                   m-panel = bid>>4 -> same-XCD pairs share the A-panel.
// V  (bids 512..1023): n = idx&7 (one per XCD), m = idx>>3.
__global__ __launch_bounds__(256) void gemm_qkv(
    const float* __restrict__ x, const u16* __restrict__ WTqkv, const u16* __restrict__ WTv,
    u16* __restrict__ Qb, u16* __restrict__ Kb, u16* __restrict__ VT,
    const float* __restrict__ fc, const float* __restrict__ fs) {
  __shared__ u16 smem[2 * 16384];   // 64 KB
  const int bid = blockIdx.x;
  if (bid < 512) {
    const int bx = ((bid & 7) << 1) | ((bid >> 3) & 1);
    const int by = bid >> 4;
    gemm_body<4, 0>(smem, bx, by, x, nullptr, WTqkv, Qb, Kb, nullptr, nullptr, fc, fs);
  } else {
    const int idx = bid - 512;
    gemm_body<2, 1>(smem, idx & 7, idx >> 3, x, nullptr, WTv,
                    nullptr, nullptr, VT, nullptr, nullptr, nullptr);
  }
}

__global__ __launch_bounds__(256) void gemm_out_k(
    const u16* __restrict__ Ob, const u16* __restrict__ WTo, float* __restrict__ out) {
  __shared__ u16 smem[2 * 12288];
  const int bid = blockIdx.x;                  // 512 blocks: n = bid&7, m = bid>>3
  gemm_body<2, 2>(smem, bid & 7, bid >> 3, nullptr, Ob, WTo,
                  nullptr, nullptr, nullptr, out, nullptr, nullptr);
}

// ---------------- flash attention (causal), paired q-tiles, KVB=128 (R16 proven) ----------------
__global__ __launch_bounds__(256) void attn_k(
    const u16* __restrict__ Qb, const u16* __restrict__ Kb,
    const u16* __restrict__ VT, u16* __restrict__ Ob) {
  __shared__ u16 K2[2][8192];   // [kv=128][d=64], rows 128B, slot^=(row&7)
  __shared__ u16 V2[2][8192];   // [d=64][kv=128], rows 256B, slot^=(d&15)
  __shared__ u16 Pl[4][2048];   // per wave [q=16][kv=128], rows 256B, slot^=(lr&15)
  const int tid = threadIdx.x, w = tid >> 6, lane = tid & 63;
  const int lr = lane & 15, lg = lane >> 4;
  const int bid = blockIdx.x;
  const int xcd = bid & 7, i = bid >> 3;          // i in 0..63
  const int bh = xcd * 4 + (i & 3);
  const int pair = i >> 2;                        // 0..15
  const int b = bh >> 4, h = bh & 15;
  const u16* Qp = Qb + (size_t)bh * NS * HDIM;
  const u16* Kp = Kb + (size_t)bh * NS * HDIM;
  const u16* Vp = VT + (size_t)bh * NS * HDIM;    // [d][s]

  int kf_off[8][2], vb_off[4][4], pw_off[8], pa_off[4];
#pragma unroll
  for (int u = 0; u < 8; ++u) {
    const int kvr = (u << 4) + lr;
#pragma unroll
    for (int c = 0; c < 2; ++c)
      kf_off[u][c] = kvr * 64 + ((((c << 6) + (lg << 4)) ^ ((kvr & 7) << 4)) >> 1);
  }
#pragma unroll
  for (int dn = 0; dn < 4; ++dn) {
    const int d = (dn << 4) + lr;
#pragma unroll
    for (int ks = 0; ks < 4; ++ks)
      vb_off[dn][ks] = d * 128 + ((((ks << 6) + (lg << 4)) ^ ((d & 15) << 4)) >> 1);
  }
#pragma unroll
  for (int u = 0; u < 8; ++u)
    pw_off[u] = lr * 128 + ((((u << 5) + (lg << 3)) ^ ((lr & 15) << 4)) >> 1);
#pragma unroll
  for (int ks = 0; ks < 4; ++ks)
    pa_off[ks] = lr * 128 + ((((ks << 6) + (lg << 4)) ^ ((lr & 15) << 4)) >> 1);
  u16* Pw = &Pl[w][0];

  const int rr = tid >> 3, slot = tid & 7;
  const int ksoff = ((slot ^ (rr & 7)) << 3);
  const u16* kg = Kp + (size_t)rr * HDIM + ksoff;
  const int vr = tid >> 4, vslot = tid & 15;
  const int vsoff = ((vslot ^ vr) << 3);
  const u16* vg = Vp + (size_t)vr * NS + vsoff;

#define STAGE(BUFI, KV0)                                                            \
  {                                                                                 \
    _Pragma("unroll")                                                               \
    for (int c = 0; c < 4; ++c) {                                                   \
      gld_lds16(kg + (size_t)((KV0) + c * 32) * HDIM, &K2[BUFI][c * 2048 + w * 512]); \
      gld_lds16(vg + (size_t)(c * 16) * NS + (KV0),   &V2[BUFI][c * 2048 + w * 512]); \
    }                                                                               \
  }

#define STEP(BUF, KVT)                                                            \
  {                                                                               \
    const int kv0 = (KVT) << 7;                                                   \
    if ((KVT) + 1 < nst) STAGE(BUF ^ 1, kv0 + 128);                               \
    const u16* Kl = K2[BUF];                                                      \
    const u16* Vl = V2[BUF];                                                      \
    f32x4 st[8] = {};                                                             \
    __builtin_amdgcn_s_setprio(1);                                                \
    _Pragma("unroll") for (int u = 0; u < 8; ++u)                                 \
      _Pragma("unroll") for (int c = 0; c < 2; ++c)                               \
        st[u] = __builtin_amdgcn_mfma_f32_16x16x32_bf16(                          \
            *(const short8*)(Kl + kf_off[u][c]), qf[c], st[u], 0, 0, 0);          \
    __builtin_amdgcn_s_setprio(0);                                                \
    if (kv0 + 127 > qw) {                                                         \
      _Pragma("unroll") for (int u = 0; u < 8; ++u)                               \
        _Pragma("unroll") for (int j = 0; j < 4; ++j) {                           \
          const int kvg = kv0 + (u << 4) + (lg << 2) + j;                         \
          if (kvg > q_col) st[u][j] = NEGBIG;                                     \
        }                                                                         \
    }                                                                             \
    _Pragma("unroll") for (int u = 0; u < 8; ++u) {                               \
      const float e0 = __builtin_amdgcn_exp2f(st[u][0]);                          \
      const float e1 = __builtin_amdgcn_exp2f(st[u][1]);                          \
      const float e2 = __builtin_amdgcn_exp2f(st[u][2]);                          \
      const float e3 = __builtin_amdgcn_exp2f(st[u][3]);                          \
      lacc += (e0 + e1) + (e2 + e3);                                              \
      uint2v pk;                                                                  \
      pk.x = cvt_pk_bf16(e0, e1);                                                 \
      pk.y = cvt_pk_bf16(e2, e3);                                                 \
      *(uint2v*)(Pw + pw_off[u]) = pk;                                            \
    }                                                                             \
    {                                                                             \
      short8 pa[4];                                                               \
      _Pragma("unroll") for (int ks = 0; ks < 4; ++ks)                            \
        pa[ks] = *(const short8*)(Pw + pa_off[ks]);                               \
      __builtin_amdgcn_s_setprio(1);                                              \
      _Pragma("unroll") for (int dn = 0; dn < 4; ++dn)                            \
        _Pragma("unroll") for (int ks = 0; ks < 4; ++ks)                          \
          o[dn] = __builtin_amdgcn_mfma_f32_16x16x32_bf16(                        \
              pa[ks], *(const short8*)(Vl + vb_off[dn][ks]), o[dn], 0, 0, 0);     \
      __builtin_amdgcn_s_setprio(0);                                              \
    }                                                                             \
    __syncthreads();                                                              \
  }

  for (int seg = 0; seg < 2; ++seg) {
    const int tile = seg ? pair : 31 - pair;      // long tile first, short second
    const int q0 = tile << 6;
    const int qw = q0 + w * 16;
    const int q_col = qw + lr;
    const int nst = (tile + 2) >> 1;              // KVB=128 steps

    short8 qf[2];
#pragma unroll
    for (int c = 0; c < 2; ++c)
      qf[c] = *(const short8*)(Qp + (size_t)(qw + lr) * HDIM + c * 32 + lg * 8);

    f32x4 o[4] = {};
    float lacc = 0.f;

    STAGE(0, 0);
    __syncthreads();

    int kvt = 0;
    for (; kvt + 2 <= nst; kvt += 2) {
      STEP(0, kvt);
      STEP(1, kvt + 1);
    }
    if (kvt < nst) STEP(0, kvt);

    float rs = lacc;
    rs += __shfl_xor(rs, 16);
    rs += __shfl_xor(rs, 32);
    float li[4];
#pragma unroll
    for (int j = 0; j < 4; ++j) li[j] = 1.0f / __shfl(rs, (lg << 2) + j);
#pragma unroll
    for (int dn = 0; dn < 4; ++dn)
#pragma unroll
      for (int j = 0; j < 4; ++j) {
        const int m = b * NS + qw + (lg << 2) + j;
        const int col = h * 64 + dn * 16 + lr;
        Ob[(size_t)m * ND + col] = f2bf(o[dn][j] * li[j]);
      }
  }
}

extern "C" void kernel_launch(void* const* d_in, const int* in_sizes, int n_in,
                              void* d_out, int out_size, void* d_ws, size_t ws_size,
                              hipStream_t stream) {
  const float* x  = (const float*)d_in[0];
  const float* fc = (const float*)d_in[1];
  const float* fs = (const float*)d_in[2];
  const float* Wq = (const float*)d_in[3];
  const float* Wk = (const float*)d_in[4];
  const float* Wv = (const float*)d_in[5];
  const float* Wo = (const float*)d_in[6];
  float* out = (float*)d_out;
  char* ws = (char*)d_ws;

  // Workspace timeline (40 MB): no xb anymore (x read directly by gemm_qkv).
  //  0- 8MB: Ob (written by attn)
  //  8-14MB: WTqkv     14-16MB: WTo (written upfront, read at end)
  // 16-24MB: Qb        24-32MB: Kb
  // 32-40MB: VT (written DIRECTLY by V-gemm epilogue)
  u16* Ob    = (u16*)(ws);
  u16* WTqkv = (u16*)(ws + (size_t)(8u << 20));
  u16* WTo   = (u16*)(ws + (size_t)(14u << 20));
  u16* Qb    = (u16*)(ws + (size_t)(16u << 20));
  u16* Kb    = (u16*)(ws + (size_t)(24u << 20));
  u16* VT    = (u16*)(ws + (size_t)(32u << 20));
  u16* WTv   = WTqkv + (size_t)2 * ND * ND;

  prep_w<<<4096, 256, 0, stream>>>(Wq, Wk, Wv, Wo, WTqkv, WTo);
  gemm_qkv<<<1024, 256, 0, stream>>>(x, WTqkv, WTv, Qb, Kb, VT, fc, fs);
  attn_k<<<512, 256, 0, stream>>>(Qb, Kb, VT, Ob);
  gemm_out_k<<<512, 256, 0, stream>>>(Ob, WTo, out);
}

// Round 18
// 101.167 us; speedup vs baseline: 1.1485x; 1.1485x over previous
//
#include <hip/hip_runtime.h>
#include <stdint.h>

typedef unsigned short u16;
typedef __attribute__((ext_vector_type(8))) short short8;
typedef __attribute__((ext_vector_type(4))) float f32x4;
typedef __attribute__((ext_vector_type(4))) unsigned short ushort4v;
typedef __attribute__((ext_vector_type(2))) unsigned int uint2v;

#define NB 2
#define NS 2048
#define ND 1024
#define NH 16
#define HDIM 64
#define NHALF 32
#define QSCALE 0.18033688f   /* 0.125 * log2(e) : folds 1/sqrt(64) and exp->exp2 */
#define NEGBIG -3.0e38f      /* finite "-inf": exp2 -> 0, no NaN from arithmetic */

__device__ __forceinline__ float bf2f(u16 u) {
  union { unsigned u; float f; } v; v.u = ((unsigned)u) << 16; return v.f;
}
__device__ __forceinline__ u16 f2bf(float f) {
  union { float f; unsigned u; } v; v.f = f;
  unsigned r = v.u + 0x7fffu + ((v.u >> 16) & 1u);
  return (u16)(r >> 16);
}

// packs lo->bits[15:0], hi->bits[31:16], RNE — same rounding as f2bf
__device__ __forceinline__ unsigned cvt_pk_bf16(float lo, float hi) {
  unsigned r;
  asm("v_cvt_pk_bf16_f32 %0, %1, %2" : "=v"(r) : "v"(lo), "v"(hi));
  return r;
}

__device__ __forceinline__ void gld_lds16(const u16* g, u16* l) {
  void* gv = (void*)g;
  __builtin_amdgcn_global_load_lds((__attribute__((address_space(1))) void*)gv,
                                   (__attribute__((address_space(3))) void*)l, 16, 0, 0);
}

// ---------------- prep: cvt_x (blocks 0..4095) + transpose_w4 (4096..8191) ----------------
__global__ void prep(const float* __restrict__ x, u16* __restrict__ xb,
                     const float* __restrict__ W0, const float* __restrict__ W1,
                     const float* __restrict__ W2, const float* __restrict__ W3,
                     u16* __restrict__ dqkv, u16* __restrict__ dout) {
  __shared__ float tile[32][33];
  const int bid = blockIdx.x;
  if (bid < 4096) {
    int i = bid * 256 + threadIdx.x;
    float4 v = ((const float4*)x)[i];
    ushort4v o;
    o.x = f2bf(v.x); o.y = f2bf(v.y); o.z = f2bf(v.z); o.w = f2bf(v.w);
    ((ushort4v*)xb)[i] = o;
  } else {
    int idx = bid - 4096;
    const int z = idx >> 10;
    idx &= 1023;
    const int bx = idx & 31, by = idx >> 5;
    const float* W = (z == 0) ? W0 : (z == 1) ? W1 : (z == 2) ? W2 : W3;
    u16* dst = (z < 3) ? (dqkv + (size_t)z * ND * ND) : dout;
    const int n0 = bx * 32, k0 = by * 32;
    const int tx = threadIdx.x & 31, ty = threadIdx.x >> 5;   // 32x8
#pragma unroll
    for (int i = 0; i < 4; ++i)
      tile[ty + i * 8][tx] = W[(size_t)(k0 + ty + i * 8) * ND + n0 + tx];
    __syncthreads();
#pragma unroll
    for (int i = 0; i < 4; ++i)
      dst[(size_t)(n0 + ty + i * 8) * ND + k0 + tx] = f2bf(tile[tx][ty + i * 8]);
  }
}

// ---------------- shared GEMM body, BK=64, XOR-swizzled + double-buffered LDS ----------------
// MODE 0 (QK): operand-SWAPPED MFMA -> acc = (x@W)^T fragments: lane owns 4
//   consecutive d at fixed s -> RoPE+QSCALE fused, 8B stores.
// MODE 1 (V):  normal orientation, direct VT [b][h][d][s] 8B packed stores.
// MODE 2 (out): fp32 rows.
template<int MI, int MODE>
__device__ __forceinline__ void gemm_body(
    u16* smem0, int bx, int by,
    const u16* __restrict__ A, const u16* __restrict__ BT,
    u16* __restrict__ qo, u16* __restrict__ ko, u16* __restrict__ vo,
    float* __restrict__ fo,
    const float* __restrict__ cosT, const float* __restrict__ sinT) {
  constexpr int BUFSZ = MI * 2048 + 8192;
  const int tid = threadIdx.x;
  const int w = tid >> 6, lane = tid & 63;
  const int lr = lane & 15, lg = lane >> 4;
  const int bm = by * (MI * 32), bn = bx << 7;
  const int wr = (w >> 1) * (MI * 16), wc = (w & 1) << 6;
  f32x4 acc[MI][4] = {};

  const int arow = tid >> 3;
  const int aslot = (tid & 7) ^ (arow & 7);
  const u16* ags = A + (size_t)(bm + arow) * ND + (aslot << 3);
  const u16* bgs = BT + (size_t)(bn + arow) * ND + (aslot << 3);

  int af_off[MI][2], bf_off[4][2];
#pragma unroll
  for (int mi = 0; mi < MI; ++mi)
#pragma unroll
    for (int kk = 0; kk < 2; ++kk)
      af_off[mi][kk] = (wr + mi * 16 + lr) * 64 + ((((kk << 2) + lg) ^ (lr & 7)) << 3);
#pragma unroll
  for (int ni = 0; ni < 4; ++ni)
#pragma unroll
    for (int kk = 0; kk < 2; ++kk)
      bf_off[ni][kk] = (wc + ni * 16 + lr) * 64 + ((((kk << 2) + lg) ^ (lr & 7)) << 3);

  auto stage = [&](int buf, int kt) {
    u16* dst = smem0 + buf * BUFSZ;
#pragma unroll
    for (int it = 0; it < MI; ++it)
      gld_lds16(ags + it * (32 * ND) + kt, dst + it * 2048 + w * 512);
#pragma unroll
    for (int it = 0; it < 4; ++it)
      gld_lds16(bgs + it * (32 * ND) + kt, dst + MI * 2048 + it * 2048 + w * 512);
  };

  stage(0, 0);
  __syncthreads();
  int cur = 0;
  for (int kt = 0; kt < ND; kt += 64) {
    if (kt + 64 < ND) stage(cur ^ 1, kt + 64);
    const u16* As = smem0 + cur * BUFSZ;
    const u16* Bs = As + MI * 2048;
#pragma unroll
    for (int kk = 0; kk < 2; ++kk) {
      short8 af[MI], bfr[4];
#pragma unroll
      for (int mi = 0; mi < MI; ++mi)
        af[mi] = *(const short8*)(As + af_off[mi][kk]);
#pragma unroll
      for (int ni = 0; ni < 4; ++ni)
        bfr[ni] = *(const short8*)(Bs + bf_off[ni][kk]);
#pragma unroll
      for (int mi = 0; mi < MI; ++mi)
#pragma unroll
        for (int ni = 0; ni < 4; ++ni) {
          if (MODE == 0)   // swapped operands: acc = (x@W)^T fragment
            acc[mi][ni] = __builtin_amdgcn_mfma_f32_16x16x32_bf16(bfr[ni], af[mi], acc[mi][ni], 0, 0, 0);
          else
            acc[mi][ni] = __builtin_amdgcn_mfma_f32_16x16x32_bf16(af[mi], bfr[ni], acc[mi][ni], 0, 0, 0);
        }
    }
    __syncthreads();
    cur ^= 1;
  }

  if (MODE == 0) {
    // acc[mi][ni][j]: row = n = bn+wc+ni*16+(lg<<2)+j (d-dim), col = s = bm+wr+mi*16+lr
#pragma unroll
    for (int mi = 0; mi < MI; ++mi) {
      const int m = bm + wr + mi * 16 + lr;
      const int b = m >> 11, s = m & 2047;
      const float* cbase = cosT + s * NHALF;
      const float* sbase = sinT + s * NHALF;
#pragma unroll
      for (int ni = 0; ni < 4; ++ni) {
        const int n = bn + wc + ni * 16 + (lg << 2);
        const int which = n >> 10, hh = (n >> 6) & 15, d0 = n & 63;
        u16* dst = which == 0 ? qo : ko;
        const float sc = which == 0 ? QSCALE : 1.0f;
        const float2 cp = *(const float2*)(cbase + (d0 >> 1));
        const float2 sp = *(const float2*)(sbase + (d0 >> 1));
        const float v0 = acc[mi][ni][0], v1 = acc[mi][ni][1];
        const float v2 = acc[mi][ni][2], v3 = acc[mi][ni][3];
        uint2v pk;
        pk.x = cvt_pk_bf16((v0 * cp.x - v1 * sp.x) * sc, (v0 * sp.x + v1 * cp.x) * sc);
        pk.y = cvt_pk_bf16((v2 * cp.y - v3 * sp.y) * sc, (v2 * sp.y + v3 * cp.y) * sc);
        *(uint2v*)(dst + (((size_t)(b * NH + hh) * NS + s) << 6) + d0) = pk;
      }
    }
  } else if (MODE == 1) {
    // normal orientation: lane holds 4 consecutive s at fixed d -> VT[b][h][d][s]
#pragma unroll
    for (int mi = 0; mi < MI; ++mi) {
#pragma unroll
      for (int ni = 0; ni < 4; ++ni) {
        const int n = bn + wc + ni * 16 + lr;         // d-index in [0,1024)
        const int hh = n >> 6, d = n & 63;
        const int m0 = bm + wr + mi * 16 + (lg << 2);
        const int b = m0 >> 11, s0 = m0 & 2047;
        uint2v pk;
        pk.x = cvt_pk_bf16(acc[mi][ni][0], acc[mi][ni][1]);
        pk.y = cvt_pk_bf16(acc[mi][ni][2], acc[mi][ni][3]);
        *(uint2v*)(vo + ((size_t)(b * NH + hh) * HDIM + d) * NS + s0) = pk;
      }
    }
  } else {
#pragma unroll
    for (int mi = 0; mi < MI; ++mi)
#pragma unroll
      for (int ni = 0; ni < 4; ++ni)
#pragma unroll
        for (int j = 0; j < 4; ++j) {
          const int m = bm + wr + mi * 16 + (lg << 2) + j;
          const int n = bn + wc + ni * 16 + lr;
          fo[(size_t)m * ND + n] = acc[mi][ni][j];
        }
  }
}

// Merged QKV projection: blocks 0..511 = QK (MI=4, fused RoPE), 512..1023 = V (MI=2 -> VT)
__global__ __launch_bounds__(256) void gemm_qkv(
    const u16* __restrict__ xb, const u16* __restrict__ WTqkv, const u16* __restrict__ WTv,
    u16* __restrict__ Qb, u16* __restrict__ Kb, u16* __restrict__ VT,
    const float* __restrict__ fc, const float* __restrict__ fs) {
  __shared__ u16 smem[2 * 16384];   // 64 KB: QK path 2x16384; V path uses 2x12288
  const int bid = blockIdx.x;
  if (bid < 512) {
    gemm_body<4, 0>(smem, bid & 15, bid >> 4, xb, WTqkv, Qb, Kb, nullptr, nullptr, fc, fs);
  } else {
    const int idx = bid - 512;
    gemm_body<2, 1>(smem, idx & 7, idx >> 3, xb, WTv, nullptr, nullptr, VT, nullptr, nullptr, nullptr);
  }
}

// out-proj: MI=1 (32x128 tiles) -> 1024 blocks = 4 blocks/CU (LDS 40 KB)
__global__ __launch_bounds__(256) void gemm_out_k(
    const u16* __restrict__ Ob, const u16* __restrict__ WTo, float* __restrict__ out) {
  __shared__ u16 smem[2 * 10240];
  const int bid = blockIdx.x;                  // n = bid&7, m = bid>>3 (128 panels)
  gemm_body<1, 2>(smem, bid & 7, bid >> 3, Ob, WTo, nullptr, nullptr, nullptr, out, nullptr, nullptr);
}

// ---------------- flash attention (causal), paired q-tiles, KVB=128 (R16 proven) ----------------
__global__ __launch_bounds__(256) void attn_k(
    const u16* __restrict__ Qb, const u16* __restrict__ Kb,
    const u16* __restrict__ VT, u16* __restrict__ Ob) {
  __shared__ u16 K2[2][8192];   // [kv=128][d=64], rows 128B, slot^=(row&7)
  __shared__ u16 V2[2][8192];   // [d=64][kv=128], rows 256B, slot^=(d&15)
  __shared__ u16 Pl[4][2048];   // per wave [q=16][kv=128], rows 256B, slot^=(lr&15)
  const int tid = threadIdx.x, w = tid >> 6, lane = tid & 63;
  const int lr = lane & 15, lg = lane >> 4;
  const int bid = blockIdx.x;
  const int xcd = bid & 7, i = bid >> 3;          // i in 0..63
  const int bh = xcd * 4 + (i & 3);
  const int pair = i >> 2;                        // 0..15
  const int b = bh >> 4, h = bh & 15;
  const u16* Qp = Qb + (size_t)bh * NS * HDIM;
  const u16* Kp = Kb + (size_t)bh * NS * HDIM;
  const u16* Vp = VT + (size_t)bh * NS * HDIM;    // [d][s]

  int kf_off[8][2], vb_off[4][4], pw_off[8], pa_off[4];
#pragma unroll
  for (int u = 0; u < 8; ++u) {
    const int kvr = (u << 4) + lr;
#pragma unroll
    for (int c = 0; c < 2; ++c)
      kf_off[u][c] = kvr * 64 + ((((c << 6) + (lg << 4)) ^ ((kvr & 7) << 4)) >> 1);
  }
#pragma unroll
  for (int dn = 0; dn < 4; ++dn) {
    const int d = (dn << 4) + lr;
#pragma unroll
    for (int ks = 0; ks < 4; ++ks)
      vb_off[dn][ks] = d * 128 + ((((ks << 6) + (lg << 4)) ^ ((d & 15) << 4)) >> 1);
  }
#pragma unroll
  for (int u = 0; u < 8; ++u)
    pw_off[u] = lr * 128 + ((((u << 5) + (lg << 3)) ^ ((lr & 15) << 4)) >> 1);
#pragma unroll
  for (int ks = 0; ks < 4; ++ks)
    pa_off[ks] = lr * 128 + ((((ks << 6) + (lg << 4)) ^ ((lr & 15) << 4)) >> 1);
  u16* Pw = &Pl[w][0];

  const int rr = tid >> 3, slot = tid & 7;
  const int ksoff = ((slot ^ (rr & 7)) << 3);
  const u16* kg = Kp + (size_t)rr * HDIM + ksoff;
  const int vr = tid >> 4, vslot = tid & 15;
  const int vsoff = ((vslot ^ vr) << 3);
  const u16* vg = Vp + (size_t)vr * NS + vsoff;

#define STAGE(BUFI, KV0)                                                            \
  {                                                                                 \
    _Pragma("unroll")                                                               \
    for (int c = 0; c < 4; ++c) {                                                   \
      gld_lds16(kg + (size_t)((KV0) + c * 32) * HDIM, &K2[BUFI][c * 2048 + w * 512]); \
      gld_lds16(vg + (size_t)(c * 16) * NS + (KV0),   &V2[BUFI][c * 2048 + w * 512]); \
    }                                                                               \
  }

#define STEP(BUF, KVT)                                                            \
  {                                                                               \
    const int kv0 = (KVT) << 7;                                                   \
    if ((KVT) + 1 < nst) STAGE(BUF ^ 1, kv0 + 128);                               \
    const u16* Kl = K2[BUF];                                                      \
    const u16* Vl = V2[BUF];                                                      \
    f32x4 st[8] = {};                                                             \
    __builtin_amdgcn_s_setprio(1);                                                \
    _Pragma("unroll") for (int u = 0; u < 8; ++u)                                 \
      _Pragma("unroll") for (int c = 0; c < 2; ++c)                               \
        st[u] = __builtin_amdgcn_mfma_f32_16x16x32_bf16(                          \
            *(const short8*)(Kl + kf_off[u][c]), qf[c], st[u], 0, 0, 0);          \
    __builtin_amdgcn_s_setprio(0);                                                \
    if (kv0 + 127 > qw) {                                                         \
      _Pragma("unroll") for (int u = 0; u < 8; ++u)                               \
        _Pragma("unroll") for (int j = 0; j < 4; ++j) {                           \
          const int kvg = kv0 + (u << 4) + (lg << 2) + j;                         \
          if (kvg > q_col) st[u][j] = NEGBIG;                                     \
        }                                                                         \
    }                                                                             \
    _Pragma("unroll") for (int u = 0; u < 8; ++u) {                               \
      const float e0 = __builtin_amdgcn_exp2f(st[u][0]);                          \
      const float e1 = __builtin_amdgcn_exp2f(st[u][1]);                          \
      const float e2 = __builtin_amdgcn_exp2f(st[u][2]);                          \
      const float e3 = __builtin_amdgcn_exp2f(st[u][3]);                          \
      lacc += (e0 + e1) + (e2 + e3);                                              \
      uint2v pk;                                                                  \
      pk.x = cvt_pk_bf16(e0, e1);                                                 \
      pk.y = cvt_pk_bf16(e2, e3);                                                 \
      *(uint2v*)(Pw + pw_off[u]) = pk;                                            \
    }                                                                             \
    {                                                                             \
      short8 pa[4];                                                               \
      _Pragma("unroll") for (int ks = 0; ks < 4; ++ks)                            \
        pa[ks] = *(const short8*)(Pw + pa_off[ks]);                               \
      __builtin_amdgcn_s_setprio(1);                                              \
      _Pragma("unroll") for (int dn = 0; dn < 4; ++dn)                            \
        _Pragma("unroll") for (int ks = 0; ks < 4; ++ks)                          \
          o[dn] = __builtin_amdgcn_mfma_f32_16x16x32_bf16(                        \
              pa[ks], *(const short8*)(Vl + vb_off[dn][ks]), o[dn], 0, 0, 0);     \
      __builtin_amdgcn_s_setprio(0);                                              \
    }                                                                             \
    __syncthreads();                                                              \
  }

  for (int seg = 0; seg < 2; ++seg) {
    const int tile = seg ? pair : 31 - pair;      // long tile first, short second
    const int q0 = tile << 6;
    const int qw = q0 + w * 16;
    const int q_col = qw + lr;
    const int nst = (tile + 2) >> 1;              // KVB=128 steps

    short8 qf[2];
#pragma unroll
    for (int c = 0; c < 2; ++c)
      qf[c] = *(const short8*)(Qp + (size_t)(qw + lr) * HDIM + c * 32 + lg * 8);

    f32x4 o[4] = {};
    float lacc = 0.f;

    STAGE(0, 0);
    __syncthreads();

    int kvt = 0;
    for (; kvt + 2 <= nst; kvt += 2) {
      STEP(0, kvt);
      STEP(1, kvt + 1);
    }
    if (kvt < nst) STEP(0, kvt);

    float rs = lacc;
    rs += __shfl_xor(rs, 16);
    rs += __shfl_xor(rs, 32);
    float li[4];
#pragma unroll
    for (int j = 0; j < 4; ++j) li[j] = 1.0f / __shfl(rs, (lg << 2) + j);
#pragma unroll
    for (int dn = 0; dn < 4; ++dn)
#pragma unroll
      for (int j = 0; j < 4; ++j) {
        const int m = b * NS + qw + (lg << 2) + j;
        const int col = h * 64 + dn * 16 + lr;
        Ob[(size_t)m * ND + col] = f2bf(o[dn][j] * li[j]);
      }
  }
}

extern "C" void kernel_launch(void* const* d_in, const int* in_sizes, int n_in,
                              void* d_out, int out_size, void* d_ws, size_t ws_size,
                              hipStream_t stream) {
  const float* x  = (const float*)d_in[0];
  const float* fc = (const float*)d_in[1];
  const float* fs = (const float*)d_in[2];
  const float* Wq = (const float*)d_in[3];
  const float* Wk = (const float*)d_in[4];
  const float* Wv = (const float*)d_in[5];
  const float* Wo = (const float*)d_in[6];
  float* out = (float*)d_out;
  char* ws = (char*)d_ws;

  // Workspace timeline (40 MB):
  //  0- 8MB: xb (dead after gemms) -> Ob
  //  8-14MB: WTqkv     14-16MB: WTo (written upfront, read at end)
  // 16-24MB: Qb        24-32MB: Kb
  // 32-40MB: VT (written DIRECTLY by V-gemm epilogue)
  u16* xb    = (u16*)(ws);
  u16* Ob    = (u16*)(ws);
  u16* WTqkv = (u16*)(ws + (size_t)(8u << 20));
  u16* WTo   = (u16*)(ws + (size_t)(14u << 20));
  u16* Qb    = (u16*)(ws + (size_t)(16u << 20));
  u16* Kb    = (u16*)(ws + (size_t)(24u << 20));
  u16* VT    = (u16*)(ws + (size_t)(32u << 20));
  u16* WTv   = WTqkv + (size_t)2 * ND * ND;

  prep<<<8192, 256, 0, stream>>>(x, xb, Wq, Wk, Wv, Wo, WTqkv, WTo);
  gemm_qkv<<<1024, 256, 0, stream>>>(xb, WTqkv, WTv, Qb, Kb, VT, fc, fs);
  attn_k<<<512, 256, 0, stream>>>(Qb, Kb, VT, Ob);
  gemm_out_k<<<1024, 256, 0, stream>>>(Ob, WTo, out);
}

// Round 19
// 99.324 us; speedup vs baseline: 1.1698x; 1.0186x over previous
//
#include <hip/hip_runtime.h>
#include <stdint.h>

typedef unsigned short u16;
typedef __attribute__((ext_vector_type(8))) short short8;
typedef __attribute__((ext_vector_type(4))) float f32x4;
typedef __attribute__((ext_vector_type(4))) unsigned short ushort4v;
typedef __attribute__((ext_vector_type(2))) unsigned int uint2v;

#define NB 2
#define NS 2048
#define ND 1024
#define NH 16
#define HDIM 64
#define NHALF 32
#define QSCALE 0.18033688f   /* 0.125 * log2(e) : folds 1/sqrt(64) and exp->exp2 */
#define NEGBIG -3.0e38f      /* finite "-inf": exp2 -> 0, no NaN from arithmetic */

__device__ __forceinline__ float bf2f(u16 u) {
  union { unsigned u; float f; } v; v.u = ((unsigned)u) << 16; return v.f;
}
__device__ __forceinline__ u16 f2bf(float f) {
  union { float f; unsigned u; } v; v.f = f;
  unsigned r = v.u + 0x7fffu + ((v.u >> 16) & 1u);
  return (u16)(r >> 16);
}

// packs lo->bits[15:0], hi->bits[31:16], RNE — same rounding as f2bf
__device__ __forceinline__ unsigned cvt_pk_bf16(float lo, float hi) {
  unsigned r;
  asm("v_cvt_pk_bf16_f32 %0, %1, %2" : "=v"(r) : "v"(lo), "v"(hi));
  return r;
}

__device__ __forceinline__ void gld_lds16(const u16* g, u16* l) {
  void* gv = (void*)g;
  __builtin_amdgcn_global_load_lds((__attribute__((address_space(1))) void*)gv,
                                   (__attribute__((address_space(3))) void*)l, 16, 0, 0);
}

// ---------------- prep: cvt_x (blocks 0..4095) + transpose_w4 (4096..8191) ----------------
__global__ void prep(const float* __restrict__ x, u16* __restrict__ xb,
                     const float* __restrict__ W0, const float* __restrict__ W1,
                     const float* __restrict__ W2, const float* __restrict__ W3,
                     u16* __restrict__ dqkv, u16* __restrict__ dout) {
  __shared__ float tile[32][33];
  const int bid = blockIdx.x;
  if (bid < 4096) {
    int i = bid * 256 + threadIdx.x;
    float4 v = ((const float4*)x)[i];
    ushort4v o;
    o.x = f2bf(v.x); o.y = f2bf(v.y); o.z = f2bf(v.z); o.w = f2bf(v.w);
    ((ushort4v*)xb)[i] = o;
  } else {
    int idx = bid - 4096;
    const int z = idx >> 10;
    idx &= 1023;
    const int bx = idx & 31, by = idx >> 5;
    const float* W = (z == 0) ? W0 : (z == 1) ? W1 : (z == 2) ? W2 : W3;
    u16* dst = (z < 3) ? (dqkv + (size_t)z * ND * ND) : dout;
    const int n0 = bx * 32, k0 = by * 32;
    const int tx = threadIdx.x & 31, ty = threadIdx.x >> 5;   // 32x8
#pragma unroll
    for (int i = 0; i < 4; ++i)
      tile[ty + i * 8][tx] = W[(size_t)(k0 + ty + i * 8) * ND + n0 + tx];
    __syncthreads();
#pragma unroll
    for (int i = 0; i < 4; ++i)
      dst[(size_t)(n0 + ty + i * 8) * ND + k0 + tx] = f2bf(tile[tx][ty + i * 8]);
  }
}

// ---------------- shared GEMM body, BK=64, XOR-swizzled + double-buffered LDS ----------------
// MODE 0 (QK): operand-SWAPPED MFMA -> acc = (x@W)^T fragments: lane owns 4
//   consecutive d at fixed s -> RoPE+QSCALE fused, 8B stores.
// MODE 1 (V):  normal orientation, direct VT [b][h][d][s] 8B packed stores.
// MODE 2 (out): fp32 rows.
template<int MI, int MODE>
__device__ __forceinline__ void gemm_body(
    u16* smem0, int bx, int by,
    const u16* __restrict__ A, const u16* __restrict__ BT,
    u16* __restrict__ qo, u16* __restrict__ ko, u16* __restrict__ vo,
    float* __restrict__ fo,
    const float* __restrict__ cosT, const float* __restrict__ sinT) {
  constexpr int BUFSZ = MI * 2048 + 8192;
  const int tid = threadIdx.x;
  const int w = tid >> 6, lane = tid & 63;
  const int lr = lane & 15, lg = lane >> 4;
  const int bm = by * (MI * 32), bn = bx << 7;
  const int wr = (w >> 1) * (MI * 16), wc = (w & 1) << 6;
  f32x4 acc[MI][4] = {};

  const int arow = tid >> 3;
  const int aslot = (tid & 7) ^ (arow & 7);
  const u16* ags = A + (size_t)(bm + arow) * ND + (aslot << 3);
  const u16* bgs = BT + (size_t)(bn + arow) * ND + (aslot << 3);

  int af_off[MI][2], bf_off[4][2];
#pragma unroll
  for (int mi = 0; mi < MI; ++mi)
#pragma unroll
    for (int kk = 0; kk < 2; ++kk)
      af_off[mi][kk] = (wr + mi * 16 + lr) * 64 + ((((kk << 2) + lg) ^ (lr & 7)) << 3);
#pragma unroll
  for (int ni = 0; ni < 4; ++ni)
#pragma unroll
    for (int kk = 0; kk < 2; ++kk)
      bf_off[ni][kk] = (wc + ni * 16 + lr) * 64 + ((((kk << 2) + lg) ^ (lr & 7)) << 3);

  auto stage = [&](int buf, int kt) {
    u16* dst = smem0 + buf * BUFSZ;
#pragma unroll
    for (int it = 0; it < MI; ++it)
      gld_lds16(ags + it * (32 * ND) + kt, dst + it * 2048 + w * 512);
#pragma unroll
    for (int it = 0; it < 4; ++it)
      gld_lds16(bgs + it * (32 * ND) + kt, dst + MI * 2048 + it * 2048 + w * 512);
  };

  stage(0, 0);
  __syncthreads();
  int cur = 0;
  for (int kt = 0; kt < ND; kt += 64) {
    if (kt + 64 < ND) stage(cur ^ 1, kt + 64);
    const u16* As = smem0 + cur * BUFSZ;
    const u16* Bs = As + MI * 2048;
#pragma unroll
    for (int kk = 0; kk < 2; ++kk) {
      short8 af[MI], bfr[4];
#pragma unroll
      for (int mi = 0; mi < MI; ++mi)
        af[mi] = *(const short8*)(As + af_off[mi][kk]);
#pragma unroll
      for (int ni = 0; ni < 4; ++ni)
        bfr[ni] = *(const short8*)(Bs + bf_off[ni][kk]);
#pragma unroll
      for (int mi = 0; mi < MI; ++mi)
#pragma unroll
        for (int ni = 0; ni < 4; ++ni) {
          if (MODE == 0)   // swapped operands: acc = (x@W)^T fragment
            acc[mi][ni] = __builtin_amdgcn_mfma_f32_16x16x32_bf16(bfr[ni], af[mi], acc[mi][ni], 0, 0, 0);
          else
            acc[mi][ni] = __builtin_amdgcn_mfma_f32_16x16x32_bf16(af[mi], bfr[ni], acc[mi][ni], 0, 0, 0);
        }
    }
    __syncthreads();
    cur ^= 1;
  }

  if (MODE == 0) {
    // acc[mi][ni][j]: row = n = bn+wc+ni*16+(lg<<2)+j (d-dim), col = s = bm+wr+mi*16+lr
#pragma unroll
    for (int mi = 0; mi < MI; ++mi) {
      const int m = bm + wr + mi * 16 + lr;
      const int b = m >> 11, s = m & 2047;
      const float* cbase = cosT + s * NHALF;
      const float* sbase = sinT + s * NHALF;
#pragma unroll
      for (int ni = 0; ni < 4; ++ni) {
        const int n = bn + wc + ni * 16 + (lg << 2);
        const int which = n >> 10, hh = (n >> 6) & 15, d0 = n & 63;
        u16* dst = which == 0 ? qo : ko;
        const float sc = which == 0 ? QSCALE : 1.0f;
        const float2 cp = *(const float2*)(cbase + (d0 >> 1));
        const float2 sp = *(const float2*)(sbase + (d0 >> 1));
        const float v0 = acc[mi][ni][0], v1 = acc[mi][ni][1];
        const float v2 = acc[mi][ni][2], v3 = acc[mi][ni][3];
        uint2v pk;
        pk.x = cvt_pk_bf16((v0 * cp.x - v1 * sp.x) * sc, (v0 * sp.x + v1 * cp.x) * sc);
        pk.y = cvt_pk_bf16((v2 * cp.y - v3 * sp.y) * sc, (v2 * sp.y + v3 * cp.y) * sc);
        *(uint2v*)(dst + (((size_t)(b * NH + hh) * NS + s) << 6) + d0) = pk;
      }
    }
  } else if (MODE == 1) {
    // normal orientation: lane holds 4 consecutive s at fixed d -> VT[b][h][d][s]
#pragma unroll
    for (int mi = 0; mi < MI; ++mi) {
#pragma unroll
      for (int ni = 0; ni < 4; ++ni) {
        const int n = bn + wc + ni * 16 + lr;         // d-index in [0,1024)
        const int hh = n >> 6, d = n & 63;
        const int m0 = bm + wr + mi * 16 + (lg << 2);
        const int b = m0 >> 11, s0 = m0 & 2047;
        uint2v pk;
        pk.x = cvt_pk_bf16(acc[mi][ni][0], acc[mi][ni][1]);
        pk.y = cvt_pk_bf16(acc[mi][ni][2], acc[mi][ni][3]);
        *(uint2v*)(vo + ((size_t)(b * NH + hh) * HDIM + d) * NS + s0) = pk;
      }
    }
  } else {
#pragma unroll
    for (int mi = 0; mi < MI; ++mi)
#pragma unroll
      for (int ni = 0; ni < 4; ++ni)
#pragma unroll
        for (int j = 0; j < 4; ++j) {
          const int m = bm + wr + mi * 16 + (lg << 2) + j;
          const int n = bn + wc + ni * 16 + lr;
          fo[(size_t)m * ND + n] = acc[mi][ni][j];
        }
  }
}

// Merged QKV projection, A-LOCAL XCD mapping (T1): assuming XCD = bid%8, each
// XCD owns a contiguous group of m-panels so the LARGE operand (A = xb) is
// fetched into exactly one XCD's L2; B panels are the (smaller) cross-XCD set.
// QK  (bids 0..511):  bid = {xcd:3}{mg:2}{bx:4} -> by = xcd*4 + mg (0..31), bx 0..15
// V   (bids 512..1023): idx = {xcd:3}{mg:3}{bx:3} -> by = xcd*8 + mg (0..63), bx 0..7
__global__ __launch_bounds__(256) void gemm_qkv(
    const u16* __restrict__ xb, const u16* __restrict__ WTqkv, const u16* __restrict__ WTv,
    u16* __restrict__ Qb, u16* __restrict__ Kb, u16* __restrict__ VT,
    const float* __restrict__ fc, const float* __restrict__ fs) {
  __shared__ u16 smem[2 * 16384];   // 64 KB: QK path 2x16384; V path uses 2x12288
  const int bid = blockIdx.x;
  if (bid < 512) {
    const int by = ((bid & 7) << 2) | ((bid >> 3) & 3);
    const int bx = bid >> 5;
    gemm_body<4, 0>(smem, bx, by, xb, WTqkv, Qb, Kb, nullptr, nullptr, fc, fs);
  } else {
    const int idx = bid - 512;
    const int by = ((idx & 7) << 3) | ((idx >> 3) & 7);
    const int bx = idx >> 6;
    gemm_body<2, 1>(smem, bx, by, xb, WTv, nullptr, nullptr, VT, nullptr, nullptr, nullptr);
  }
}

// out-proj: MI=1 (32x128 tiles), 1024 blocks = 4 blocks/CU; A-local mapping:
// bid = {xcd:3}{mg:4}{bx:3} -> by = xcd*16 + mg (0..127), bx 0..7
__global__ __launch_bounds__(256) void gemm_out_k(
    const u16* __restrict__ Ob, const u16* __restrict__ WTo, float* __restrict__ out) {
  __shared__ u16 smem[2 * 10240];
  const int bid = blockIdx.x;
  const int by = ((bid & 7) << 4) | ((bid >> 3) & 15);
  const int bx = bid >> 7;
  gemm_body<1, 2>(smem, bx, by, Ob, WTo, nullptr, nullptr, nullptr, out, nullptr, nullptr);
}

// ---------------- flash attention (causal), paired q-tiles, KVB=128 (R16 proven) ----------------
__global__ __launch_bounds__(256) void attn_k(
    const u16* __restrict__ Qb, const u16* __restrict__ Kb,
    const u16* __restrict__ VT, u16* __restrict__ Ob) {
  __shared__ u16 K2[2][8192];   // [kv=128][d=64], rows 128B, slot^=(row&7)
  __shared__ u16 V2[2][8192];   // [d=64][kv=128], rows 256B, slot^=(d&15)
  __shared__ u16 Pl[4][2048];   // per wave [q=16][kv=128], rows 256B, slot^=(lr&15)
  const int tid = threadIdx.x, w = tid >> 6, lane = tid & 63;
  const int lr = lane & 15, lg = lane >> 4;
  const int bid = blockIdx.x;
  const int xcd = bid & 7, i = bid >> 3;          // i in 0..63
  const int bh = xcd * 4 + (i & 3);
  const int pair = i >> 2;                        // 0..15
  const int b = bh >> 4, h = bh & 15;
  const u16* Qp = Qb + (size_t)bh * NS * HDIM;
  const u16* Kp = Kb + (size_t)bh * NS * HDIM;
  const u16* Vp = VT + (size_t)bh * NS * HDIM;    // [d][s]

  int kf_off[8][2], vb_off[4][4], pw_off[8], pa_off[4];
#pragma unroll
  for (int u = 0; u < 8; ++u) {
    const int kvr = (u << 4) + lr;
#pragma unroll
    for (int c = 0; c < 2; ++c)
      kf_off[u][c] = kvr * 64 + ((((c << 6) + (lg << 4)) ^ ((kvr & 7) << 4)) >> 1);
  }
#pragma unroll
  for (int dn = 0; dn < 4; ++dn) {
    const int d = (dn << 4) + lr;
#pragma unroll
    for (int ks = 0; ks < 4; ++ks)
      vb_off[dn][ks] = d * 128 + ((((ks << 6) + (lg << 4)) ^ ((d & 15) << 4)) >> 1);
  }
#pragma unroll
  for (int u = 0; u < 8; ++u)
    pw_off[u] = lr * 128 + ((((u << 5) + (lg << 3)) ^ ((lr & 15) << 4)) >> 1);
#pragma unroll
  for (int ks = 0; ks < 4; ++ks)
    pa_off[ks] = lr * 128 + ((((ks << 6) + (lg << 4)) ^ ((lr & 15) << 4)) >> 1);
  u16* Pw = &Pl[w][0];

  const int rr = tid >> 3, slot = tid & 7;
  const int ksoff = ((slot ^ (rr & 7)) << 3);
  const u16* kg = Kp + (size_t)rr * HDIM + ksoff;
  const int vr = tid >> 4, vslot = tid & 15;
  const int vsoff = ((vslot ^ vr) << 3);
  const u16* vg = Vp + (size_t)vr * NS + vsoff;

#define STAGE(BUFI, KV0)                                                            \
  {                                                                                 \
    _Pragma("unroll")                                                               \
    for (int c = 0; c < 4; ++c) {                                                   \
      gld_lds16(kg + (size_t)((KV0) + c * 32) * HDIM, &K2[BUFI][c * 2048 + w * 512]); \
      gld_lds16(vg + (size_t)(c * 16) * NS + (KV0),   &V2[BUFI][c * 2048 + w * 512]); \
    }                                                                               \
  }

#define STEP(BUF, KVT)                                                            \
  {                                                                               \
    const int kv0 = (KVT) << 7;                                                   \
    if ((KVT) + 1 < nst) STAGE(BUF ^ 1, kv0 + 128);                               \
    const u16* Kl = K2[BUF];                                                      \
    const u16* Vl = V2[BUF];                                                      \
    f32x4 st[8] = {};                                                             \
    __builtin_amdgcn_s_setprio(1);                                                \
    _Pragma("unroll") for (int u = 0; u < 8; ++u)                                 \
      _Pragma("unroll") for (int c = 0; c < 2; ++c)                               \
        st[u] = __builtin_amdgcn_mfma_f32_16x16x32_bf16(                          \
            *(const short8*)(Kl + kf_off[u][c]), qf[c], st[u], 0, 0, 0);          \
    __builtin_amdgcn_s_setprio(0);                                                \
    if (kv0 + 127 > qw) {                                                         \
      _Pragma("unroll") for (int u = 0; u < 8; ++u)                               \
        _Pragma("unroll") for (int j = 0; j < 4; ++j) {                           \
          const int kvg = kv0 + (u << 4) + (lg << 2) + j;                         \
          if (kvg > q_col) st[u][j] = NEGBIG;                                     \
        }                                                                         \
    }                                                                             \
    _Pragma("unroll") for (int u = 0; u < 8; ++u) {                               \
      const float e0 = __builtin_amdgcn_exp2f(st[u][0]);                          \
      const float e1 = __builtin_amdgcn_exp2f(st[u][1]);                          \
      const float e2 = __builtin_amdgcn_exp2f(st[u][2]);                          \
      const float e3 = __builtin_amdgcn_exp2f(st[u][3]);                          \
      lacc += (e0 + e1) + (e2 + e3);                                              \
      uint2v pk;                                                                  \
      pk.x = cvt_pk_bf16(e0, e1);                                                 \
      pk.y = cvt_pk_bf16(e2, e3);                                                 \
      *(uint2v*)(Pw + pw_off[u]) = pk;                                            \
    }                                                                             \
    {                                                                             \
      short8 pa[4];                                                               \
      _Pragma("unroll") for (int ks = 0; ks < 4; ++ks)                            \
        pa[ks] = *(const short8*)(Pw + pa_off[ks]);                               \
      __builtin_amdgcn_s_setprio(1);                                              \
      _Pragma("unroll") for (int dn = 0; dn < 4; ++dn)                            \
        _Pragma("unroll") for (int ks = 0; ks < 4; ++ks)                          \
          o[dn] = __builtin_amdgcn_mfma_f32_16x16x32_bf16(                        \
              pa[ks], *(const short8*)(Vl + vb_off[dn][ks]), o[dn], 0, 0, 0);     \
      __builtin_amdgcn_s_setprio(0);                                              \
    }                                                                             \
    __syncthreads();                                                              \
  }

  for (int seg = 0; seg < 2; ++seg) {
    const int tile = seg ? pair : 31 - pair;      // long tile first, short second
    const int q0 = tile << 6;
    const int qw = q0 + w * 16;
    const int q_col = qw + lr;
    const int nst = (tile + 2) >> 1;              // KVB=128 steps

    short8 qf[2];
#pragma unroll
    for (int c = 0; c < 2; ++c)
      qf[c] = *(const short8*)(Qp + (size_t)(qw + lr) * HDIM + c * 32 + lg * 8);

    f32x4 o[4] = {};
    float lacc = 0.f;

    STAGE(0, 0);
    __syncthreads();

    int kvt = 0;
    for (; kvt + 2 <= nst; kvt += 2) {
      STEP(0, kvt);
      STEP(1, kvt + 1);
    }
    if (kvt < nst) STEP(0, kvt);

    float rs = lacc;
    rs += __shfl_xor(rs, 16);
    rs += __shfl_xor(rs, 32);
    float li[4];
#pragma unroll
    for (int j = 0; j < 4; ++j) li[j] = 1.0f / __shfl(rs, (lg << 2) + j);
#pragma unroll
    for (int dn = 0; dn < 4; ++dn)
#pragma unroll
      for (int j = 0; j < 4; ++j) {
        const int m = b * NS + qw + (lg << 2) + j;
        const int col = h * 64 + dn * 16 + lr;
        Ob[(size_t)m * ND + col] = f2bf(o[dn][j] * li[j]);
      }
  }
}

extern "C" void kernel_launch(void* const* d_in, const int* in_sizes, int n_in,
                              void* d_out, int out_size, void* d_ws, size_t ws_size,
                              hipStream_t stream) {
  const float* x  = (const float*)d_in[0];
  const float* fc = (const float*)d_in[1];
  const float* fs = (const float*)d_in[2];
  const float* Wq = (const float*)d_in[3];
  const float* Wk = (const float*)d_in[4];
  const float* Wv = (const float*)d_in[5];
  const float* Wo = (const float*)d_in[6];
  float* out = (float*)d_out;
  char* ws = (char*)d_ws;

  // Workspace timeline (40 MB):
  //  0- 8MB: xb (dead after gemms) -> Ob
  //  8-14MB: WTqkv     14-16MB: WTo (written upfront, read at end)
  // 16-24MB: Qb        24-32MB: Kb
  // 32-40MB: VT (written DIRECTLY by V-gemm epilogue)
  u16* xb    = (u16*)(ws);
  u16* Ob    = (u16*)(ws);
  u16* WTqkv = (u16*)(ws + (size_t)(8u << 20));
  u16* WTo   = (u16*)(ws + (size_t)(14u << 20));
  u16* Qb    = (u16*)(ws + (size_t)(16u << 20));
  u16* Kb    = (u16*)(ws + (size_t)(24u << 20));
  u16* VT    = (u16*)(ws + (size_t)(32u << 20));
  u16* WTv   = WTqkv + (size_t)2 * ND * ND;

  prep<<<8192, 256, 0, stream>>>(x, xb, Wq, Wk, Wv, Wo, WTqkv, WTo);
  gemm_qkv<<<1024, 256, 0, stream>>>(xb, WTqkv, WTv, Qb, Kb, VT, fc, fs);
  attn_k<<<512, 256, 0, stream>>>(Qb, Kb, VT, Ob);
  gemm_out_k<<<1024, 256, 0, stream>>>(Ob, WTo, out);
}